// Round 16
// baseline (843.466 us; speedup 1.0000x reference)
//
#include <hip/hip_runtime.h>

#define NN 100000
#define NE 3200000
#define NG 256
#define H 32
#define SB ((NN + 255) / 256)    // 391 scan blocks
#define NB 98                    // dst buckets: (99999>>10)+1
#define BK_SH 10
#define PART_BLOCKS ((NE + 4095) / 4096)   // 782
#define NW 4                     // src windows
#define WSZ 25000                // nodes/window -> E-window 3.2MB < 4MB L2

typedef __attribute__((ext_vector_type(8))) short b16x8;   // 8 bf16 = 4 VGPRs
typedef __attribute__((ext_vector_type(4))) float f32x4;

union ABfrag { unsigned u[4]; b16x8 v; };

// init g=0 (pool; values >=0 so raw-bit u32 max works), hist2=0, bktcnt=0.
__global__ __launch_bounds__(256) void k_init(unsigned* __restrict__ g,
                                              uint4* __restrict__ hist2,
                                              unsigned* __restrict__ bktcnt) {
    int i = blockIdx.x * 256 + threadIdx.x;
    if (i < NG * H) g[i] = 0u;
    if (i < NN) hist2[i] = make_uint4(0u, 0u, 0u, 0u);
    if (i < NB) bktcnt[i] = 0u;
}

// Pack Wb (32x32) of both layers into MFMA B-fragments, bf16 hi/lo split.
__global__ __launch_bounds__(64) void k_packw(const float* __restrict__ W1b,
                                              const float* __restrict__ W2b,
                                              unsigned* __restrict__ Wpk) {
    int l = threadIdx.x;
    int n = l & 15, gq = l >> 4;
    for (int layer = 0; layer < 2; layer++) {
        const float* W = layer ? W2b : W1b;
        for (int h = 0; h < 2; h++) {
            unsigned hi[8], lo[8];
#pragma unroll
            for (int i = 0; i < 8; i++) {
                float w = W[(8 * gq + i) * H + h * 16 + n];
                unsigned wb = __float_as_uint(w);
                unsigned hb = wb & 0xffff0000u;
                float r = w - __uint_as_float(hb);
                hi[i] = hb;
                lo[i] = __float_as_uint(r) & 0xffff0000u;
            }
            unsigned* dh = Wpk + (((layer * 4 + h * 2 + 0) * 64) + l) * 4;
            unsigned* dl = Wpk + (((layer * 4 + h * 2 + 1) * 64) + l) * 4;
#pragma unroll
            for (int w2 = 0; w2 < 4; w2++) {
                dh[w2] = (hi[2 * w2] >> 16) | (hi[2 * w2 + 1] & 0xffff0000u);
                dl[w2] = (lo[2 * w2] >> 16) | (lo[2 * w2 + 1] & 0xffff0000u);
            }
        }
    }
}

// Per-(dst,window) histogram + per-bucket counts.
__global__ __launch_bounds__(256) void k_hist(const int* __restrict__ src,
                                              const int* __restrict__ dst,
                                              unsigned* __restrict__ hist2,
                                              unsigned* __restrict__ bktcnt) {
    __shared__ unsigned lb[NB];
    int tid = threadIdx.x;
    if (tid < NB) lb[tid] = 0u;
    __syncthreads();
    int base = blockIdx.x * 4096 + tid;
    for (int c = 0; c < 16; c++) {
        int e = base + c * 256;
        if (e < NE) {
            int d = dst[e];
            int w = src[e] / WSZ;
            atomicAdd(&hist2[(d << 2) | w], 1u);
            atomicAdd(&lb[d >> BK_SH], 1u);
        }
    }
    __syncthreads();
    if (tid < NB) {
        unsigned v = lb[tid];
        if (v) atomicAdd(&bktcnt[tid], v);
    }
}

// Block-level exclusive scan over per-node TOTALS (sum of 4 window counts).
__global__ __launch_bounds__(256) void k_scan1(const uint4* __restrict__ hist2,
                                               unsigned* __restrict__ pre,
                                               unsigned* __restrict__ bsum) {
    __shared__ unsigned sd[256];
    int tid = threadIdx.x;
    int i = blockIdx.x * 256 + tid;
    unsigned v = 0u;
    if (i < NN) { uint4 h = hist2[i]; v = h.x + h.y + h.z + h.w; }
    sd[tid] = v;
    __syncthreads();
    for (int off = 1; off < 256; off <<= 1) {
        unsigned t = (tid >= off) ? sd[tid - off] : 0u;
        __syncthreads();
        sd[tid] += t;
        __syncthreads();
    }
    if (i < NN) pre[i] = sd[tid] - v;
    if (tid == 255) bsum[blockIdx.x] = sd[255];
}

__global__ __launch_bounds__(512) void k_scan2(const unsigned* __restrict__ bsum,
                                               unsigned* __restrict__ bpre) {
    __shared__ unsigned sd[512];
    int t = threadIdx.x;
    unsigned v = (t < SB) ? bsum[t] : 0u;
    sd[t] = v;
    __syncthreads();
    for (int off = 1; off < 512; off <<= 1) {
        unsigned x = (t >= off) ? sd[t - off] : 0u;
        __syncthreads();
        sd[t] += x;
        __syncthreads();
    }
    if (t < SB) bpre[t] = sd[t] - v;
}

// cursors[i] = CSR start of node i; ends[i] = start + total count.
__global__ __launch_bounds__(256) void k_scan3(const unsigned* __restrict__ pre,
                                               const unsigned* __restrict__ bpre,
                                               const uint4* __restrict__ hist2,
                                               unsigned* __restrict__ cursors,
                                               unsigned* __restrict__ ends) {
    int i = blockIdx.x * 256 + threadIdx.x;
    if (i < NN) {
        unsigned o = pre[i] + bpre[blockIdx.x];
        uint4 h = hist2[i];
        cursors[i] = o;
        ends[i] = o + h.x + h.y + h.z + h.w;
    }
}

// Per-(node,window) scatter cursors + packed u8 counts (deg_w ~ Poisson(8)).
__global__ __launch_bounds__(256) void k_cnt(const uint4* __restrict__ hist2,
                                             const unsigned* __restrict__ cursors,
                                             uint4* __restrict__ cursors2,
                                             unsigned* __restrict__ cnt2) {
    int n = blockIdx.x * 256 + threadIdx.x;
    if (n >= NN) return;
    uint4 h = hist2[n];
    unsigned o = cursors[n];
    cursors2[n] = make_uint4(o, o + h.x, o + h.x + h.y, o + h.x + h.y + h.z);
    cnt2[n] = h.x | (h.y << 8) | (h.z << 16) | (h.w << 24);
}

// Tiny exclusive scan of the 98 bucket counts.
__global__ __launch_bounds__(128) void k_bscan(const unsigned* __restrict__ bktcnt,
                                               unsigned* __restrict__ bktbase,
                                               unsigned* __restrict__ bktcur) {
    __shared__ unsigned sd[128];
    int t = threadIdx.x;
    unsigned v = (t < NB) ? bktcnt[t] : 0u;
    sd[t] = v;
    __syncthreads();
    for (int off = 1; off < 128; off <<= 1) {
        unsigned x = (t >= off) ? sd[t - off] : 0u;
        __syncthreads();
        sd[t] += x;
        __syncthreads();
    }
    if (t < NB) { bktbase[t] = sd[t] - v; bktcur[t] = sd[t] - v; }
    if (t == 127) bktbase[NB] = NE;
}

// Pass A: partition edges into 98 dst-buckets (grouped staging writes).
// staging word = (src << 10) | (dst & 1023).
__global__ __launch_bounds__(256) void k_part(const int* __restrict__ src,
                                              const int* __restrict__ dst,
                                              unsigned* __restrict__ bktcur,
                                              unsigned* __restrict__ staging) {
    __shared__ unsigned lh[NB], lcur[NB];
    int tid = threadIdx.x;
    if (tid < NB) lh[tid] = 0u;
    __syncthreads();
    int base = blockIdx.x * 4096 + tid;
    for (int c = 0; c < 16; c++) {
        int e = base + c * 256;
        if (e < NE) atomicAdd(&lh[dst[e] >> BK_SH], 1u);
    }
    __syncthreads();
    if (tid < NB) {
        unsigned v = lh[tid];
        lcur[tid] = v ? atomicAdd(&bktcur[tid], v) : 0u;
    }
    __syncthreads();
    for (int c = 0; c < 16; c++) {
        int e = base + c * 256;
        if (e < NE) {
            int d = dst[e], s = src[e];
            unsigned off = atomicAdd(&lcur[d >> BK_SH], 1u);
            staging[off] = ((unsigned)s << BK_SH) | (unsigned)(d & ((1 << BK_SH) - 1));
        }
    }
}

// Pass B: staging -> srcS ordered by (dst, src-window). Bucket windows keep the
// writes L2-resident.
__global__ __launch_bounds__(256) void k_scat2(const unsigned* __restrict__ staging,
                                               const unsigned* __restrict__ bktbase,
                                               unsigned* __restrict__ cursors2,
                                               unsigned* __restrict__ srcS) {
    int i = blockIdx.x * 256 + threadIdx.x;   // grid covers exactly NE
    unsigned p = staging[i];
    int lo = 0, hi = NB - 1;                  // find b: bktbase[b] <= i < [b+1]
    while (lo < hi) {
        int mid = (lo + hi + 1) >> 1;
        if ((unsigned)i >= bktbase[mid]) lo = mid; else hi = mid - 1;
    }
    int d = (lo << BK_SH) | (int)(p & ((1u << BK_SH) - 1));
    unsigned s = p >> BK_SH;
    int w = (int)s / WSZ;
    unsigned slot = atomicAdd(&cursors2[(d << 2) | w], 1u);
    srcS[slot] = s;
}

// Layer-1 src-side precompute:
//   E1[n][k] = b1a[k] + sum_i pos[n][i]*(W1a[i][k] + W1a[3+i][k])
__global__ __launch_bounds__(256) void k_pre1(const float* __restrict__ pos,
                                              const float* __restrict__ W1a,
                                              const float* __restrict__ b1a,
                                              float* __restrict__ E) {
    int n = blockIdx.x * 256 + threadIdx.x;
    if (n >= NN) return;
    float p0 = pos[3 * n], p1 = pos[3 * n + 1], p2 = pos[3 * n + 2];
    float ev[H];
#pragma unroll
    for (int k = 0; k < H; k++) {
        float v = b1a[k];
        v = fmaf(p0, W1a[k] + W1a[96 + k], v);
        v = fmaf(p1, W1a[32 + k] + W1a[128 + k], v);
        v = fmaf(p2, W1a[64 + k] + W1a[160 + k], v);
        ev[k] = v;
    }
    float4* E4 = (float4*)(E + (size_t)n * H);
#pragma unroll
    for (int r = 0; r < 8; r++)
        E4[r] = make_float4(ev[4 * r], ev[4 * r + 1], ev[4 * r + 2], ev[4 * r + 3]);
}

// Layer-2 src-side precompute: E2[n][k] = b2a[k] + h1[n]@W2a[0:32][k]
//   + pos[n]@W2a[32:35][k]   (h1 from layer 1, plain float, >=0)
__global__ __launch_bounds__(256) void k_pre2(const float* __restrict__ pos,
                                              const float* __restrict__ agg,
                                              const float* __restrict__ W2a,
                                              const float* __restrict__ b2a,
                                              float* __restrict__ E) {
    int n = blockIdx.x * 256 + threadIdx.x;
    if (n >= NN) return;
    float h[H];
    const float4* A4 = (const float4*)(agg + (size_t)n * H);
#pragma unroll
    for (int r = 0; r < 8; r++) {
        float4 u = A4[r];
        h[4 * r + 0] = u.x; h[4 * r + 1] = u.y;
        h[4 * r + 2] = u.z; h[4 * r + 3] = u.w;
    }
    float p0 = pos[3 * n], p1 = pos[3 * n + 1], p2 = pos[3 * n + 2];
    float ev[H];
#pragma unroll
    for (int k = 0; k < H; k++) {
        float v = b2a[k];
        v = fmaf(p0, W2a[32 * H + k], v);
        v = fmaf(p1, W2a[33 * H + k], v);
        v = fmaf(p2, W2a[34 * H + k], v);
        ev[k] = v;
    }
#pragma unroll
    for (int j = 0; j < H; j++) {
        float hj = h[j];
#pragma unroll
        for (int k = 0; k < H; k++) ev[k] = fmaf(hj, W2a[j * H + k], ev[k]);
    }
    float4* E4 = (float4*)(E + (size_t)n * H);
#pragma unroll
    for (int r = 0; r < 8; r++)
        E4[r] = make_float4(ev[4 * r], ev[4 * r + 1], ev[4 * r + 2], ev[4 * r + 3]);
}

// MFMA edge kernel, SRC-WINDOWED: pass p touches only E rows in window p
// (3.2MB -> L2-resident on every XCD). One wave = 2 nodes. Aggregation stays
// atomic-free: pass0 stores raw max, passes 1-2 RMW (one wave owns the node),
// final pass merges + bias/relu (+ pool for layer 2).
__global__ __launch_bounds__(256) void k_edge(const unsigned* __restrict__ srcS,
                                              const unsigned* __restrict__ ends,
                                              const unsigned* __restrict__ cnt2,
                                              const float* __restrict__ pos,
                                              const float* __restrict__ E,
                                              const float* __restrict__ Wf,
                                              const unsigned* __restrict__ WpkL,
                                              const float* __restrict__ bb,
                                              float* __restrict__ aggOut,
                                              const int* __restrict__ batch,
                                              unsigned* __restrict__ g,
                                              int layer2, int pass) {
    int lane = threadIdx.x & 63;
    int wv = __builtin_amdgcn_readfirstlane(blockIdx.x * 4 + (threadIdx.x >> 6));
    int row = lane & 15;       // A row (edge within tile)
    int j0 = (lane >> 4) << 3; // k-block start (channel j for t-generation)
    ABfrag b0h, b0l, b1h, b1l;
    {
        const uint4* W4 = (const uint4*)WpkL;
        *(uint4*)b0h.u = W4[0 * 64 + lane];
        *(uint4*)b0l.u = W4[1 * 64 + lane];
        *(uint4*)b1h.u = W4[2 * 64 + lane];
        *(uint4*)b1l.u = W4[3 * 64 + lane];
    }
    float wf0[8], wf1[8], wf2[8];
#pragma unroll
    for (int q = 0; q < 8; q++) {
        wf0[q] = Wf[j0 + q];
        wf1[q] = Wf[32 + j0 + q];
        wf2[q] = Wf[64 + j0 + q];
    }
    const f32x4 z = {0.f, 0.f, 0.f, 0.f};
    bool fin = (pass == NW - 1);
#pragma unroll 1
    for (int nn = 0; nn < 2; nn++) {
        int node = wv * 2 + nn;
        unsigned start = (node == 0) ? 0u : ends[node - 1];
        unsigned c4 = cnt2[node];
        unsigned c0 = c4 & 255u, c1 = (c4 >> 8) & 255u, c2 = (c4 >> 16) & 255u;
        unsigned off = start, dw;
        if (pass == 0)      { dw = c0; }
        else if (pass == 1) { off += c0; dw = c1; }
        else if (pass == 2) { off += c0 + c1; dw = c2; }
        else                { off += c0 + c1 + c2; dw = c4 >> 24; }
        if (dw == 0u && pass > 0 && !fin) continue;  // nothing to merge
        f32x4 vmax0 = {-3.0e38f, -3.0e38f, -3.0e38f, -3.0e38f};
        f32x4 vmax1 = vmax0;
        if (dw > 0u) {
            float pd0 = pos[3 * node], pd1 = pos[3 * node + 1], pd2 = pos[3 * node + 2];
            float fd[8];
#pragma unroll
            for (int q = 0; q < 8; q++)
                fd[q] = fmaf(pd0, wf0[q], fmaf(pd1, wf1[q], pd2 * wf2[q]));
            int nt = ((int)dw + 15) >> 4, last = (int)dw - 1;
            for (int it = 0; it < nt; it++) {
                int e = (it << 4) + row;
                if (e > last) e = last;        // duplicate-pad (max-safe)
                int s = (int)srcS[off + e];
                const float* er = E + ((size_t)s << 5) + j0;
                float4 t0 = *(const float4*)er;
                float4 t1 = *(const float4*)(er + 4);
                float t[8] = {t0.x, t0.y, t0.z, t0.w, t1.x, t1.y, t1.z, t1.w};
                ABfrag ah, al;
#pragma unroll
                for (int w = 0; w < 4; w++) {
                    float x0 = fmaxf(t[2 * w]     - fd[2 * w],     0.f);
                    float x1 = fmaxf(t[2 * w + 1] - fd[2 * w + 1], 0.f);
                    unsigned u0 = __float_as_uint(x0), u1 = __float_as_uint(x1);
                    ah.u[w] = __builtin_amdgcn_perm(u1, u0, 0x07060302u);
                    float r0 = x0 - __uint_as_float(u0 & 0xffff0000u);
                    float r1 = x1 - __uint_as_float(u1 & 0xffff0000u);
                    al.u[w] = __builtin_amdgcn_perm(__float_as_uint(r1),
                                                    __float_as_uint(r0), 0x07060302u);
                }
                f32x4 acc0 = __builtin_amdgcn_mfma_f32_16x16x32_bf16(ah.v, b0h.v, z, 0, 0, 0);
                acc0 = __builtin_amdgcn_mfma_f32_16x16x32_bf16(al.v, b0h.v, acc0, 0, 0, 0);
                acc0 = __builtin_amdgcn_mfma_f32_16x16x32_bf16(ah.v, b0l.v, acc0, 0, 0, 0);
                f32x4 acc1 = __builtin_amdgcn_mfma_f32_16x16x32_bf16(ah.v, b1h.v, z, 0, 0, 0);
                acc1 = __builtin_amdgcn_mfma_f32_16x16x32_bf16(al.v, b1h.v, acc1, 0, 0, 0);
                acc1 = __builtin_amdgcn_mfma_f32_16x16x32_bf16(ah.v, b1l.v, acc1, 0, 0, 0);
#pragma unroll
                for (int r = 0; r < 4; r++) {
                    vmax0[r] = fmaxf(vmax0[r], acc0[r]);
                    vmax1[r] = fmaxf(vmax1[r], acc1[r]);
                }
            }
        }
        float m0 = fmaxf(fmaxf(vmax0[0], vmax0[1]), fmaxf(vmax0[2], vmax0[3]));
        float m1 = fmaxf(fmaxf(vmax1[0], vmax1[1]), fmaxf(vmax1[2], vmax1[3]));
        m0 = fmaxf(m0, __shfl_xor(m0, 16));
        m0 = fmaxf(m0, __shfl_xor(m0, 32));
        m1 = fmaxf(m1, __shfl_xor(m1, 16));
        m1 = fmaxf(m1, __shfl_xor(m1, 32));
        if (lane < H) {
            float red = (lane < 16) ? m0 : m1;       // raw max for this window
            float* ar = aggOut + (size_t)node * H;
            if (pass > 0) red = fmaxf(red, ar[lane]); // merge running max
            if (!fin) {
                ar[lane] = red;                       // pass0 initializes
            } else {
                float val = fmaxf(red + bb[lane], 0.f);  // bias+relu once
                if (!layer2) {
                    ar[lane] = val;                   // h1
                } else {
                    int b = batch[node];
                    unsigned bits = __float_as_uint(val);
                    unsigned* gb = g + ((size_t)b << 5) + lane;
                    if (bits > *gb) atomicMax(gb, bits);
                }
            }
        }
    }
}

__global__ __launch_bounds__(256) void k_out(const unsigned* __restrict__ g,
                                             const float* __restrict__ Wout,
                                             const float* __restrict__ bout,
                                             float* __restrict__ out) {
    int bidx = threadIdx.x;  // one block of 256
    float acc = bout[0];
#pragma unroll
    for (int k = 0; k < H; k++)
        acc = fmaf(__uint_as_float(g[bidx * H + k]), Wout[k], acc);
    out[bidx] = acc;
}

extern "C" void kernel_launch(void* const* d_in, const int* in_sizes, int n_in,
                              void* d_out, int out_size, void* d_ws, size_t ws_size,
                              hipStream_t stream) {
    const float* pos  = (const float*)d_in[0];
    const int* src    = (const int*)d_in[1];
    const int* dst    = src + NE;
    const int* batch  = (const int*)d_in[2];
    const float* W1a  = (const float*)d_in[3];
    const float* b1a  = (const float*)d_in[4];
    const float* W1b  = (const float*)d_in[5];
    const float* b1b  = (const float*)d_in[6];
    const float* W2a  = (const float*)d_in[7];
    const float* b2a  = (const float*)d_in[8];
    const float* W2b  = (const float*)d_in[9];
    const float* b2b  = (const float*)d_in[10];
    const float* Wout = (const float*)d_in[11];
    const float* bout = (const float*)d_in[12];
    float* out = (float*)d_out;

    const size_t SZ = (size_t)NN * H;  // 3.2M words
    float*    agg  = (float*)d_ws;                   // 12.8 MB (h1 / RMW rows)
    float*    E    = (float*)d_ws + SZ;              // 12.8 MB (E1/E2)
    unsigned* srcS = (unsigned*)d_ws + 2 * SZ;       // 12.8 MB ((dst,win)-sorted)
    unsigned* g    = (unsigned*)d_ws + 3 * SZ;       // 32 KB (pool)
    unsigned* ends = g + NG * H;                     // 400 KB (per-node CSR ends)
    unsigned* cnt2 = ends + NN;                      // 400 KB (u8x4 window counts)
    unsigned* bsum = cnt2 + NN;                      // scan partials
    unsigned* bpre = bsum + SB + 1;
    unsigned* Wpk  = bpre + SB + 1;                  // 16 KB (B-fragments)
    unsigned* bktcnt  = Wpk + 4096;                  // NB
    unsigned* bktbase = bktcnt + NB;                 // NB+1
    unsigned* bktcur  = bktbase + NB + 1;            // NB
    // Aliased temporaries (all dead before their spaces' real use):
    //   agg-space (dead until k_edge L1 pass0): hist2, pre, cursors, cursors2
    //   E-space   (dead until k_pre1):          staging (NE u32 == SZ exactly)
    uint4*    hist2    = (uint4*)agg;                       // NN uint4 (1.6MB)
    unsigned* pre      = (unsigned*)agg + 4 * NN;           // NN
    unsigned* cursors  = pre + NN;                          // NN
    uint4*    cursors2 = (uint4*)((unsigned*)agg + 6 * NN); // NN uint4 (1.6MB)
    unsigned* staging  = (unsigned*)E;

    const int NODE_BLOCKS = SB;          // 391
    const int SCAT_BLOCKS = NE / 256;    // 12500 (k_scat2, exact)
    const int EDGE_BLOCKS = NN / 8;      // 12500 (4 waves x 2 nodes, exact)

    k_init<<<NODE_BLOCKS, 256, 0, stream>>>(g, hist2, bktcnt);
    k_packw<<<1, 64, 0, stream>>>(W1b, W2b, Wpk);
    k_hist<<<PART_BLOCKS, 256, 0, stream>>>(src, dst, (unsigned*)hist2, bktcnt);
    k_scan1<<<NODE_BLOCKS, 256, 0, stream>>>(hist2, pre, bsum);
    k_scan2<<<1, 512, 0, stream>>>(bsum, bpre);
    k_scan3<<<NODE_BLOCKS, 256, 0, stream>>>(pre, bpre, hist2, cursors, ends);
    k_cnt<<<NODE_BLOCKS, 256, 0, stream>>>(hist2, cursors, cursors2, cnt2);
    k_bscan<<<1, 128, 0, stream>>>(bktcnt, bktbase, bktcur);
    k_part<<<PART_BLOCKS, 256, 0, stream>>>(src, dst, bktcur, staging);
    k_scat2<<<SCAT_BLOCKS, 256, 0, stream>>>(staging, bktbase,
                                             (unsigned*)cursors2, srcS);
    k_pre1<<<NODE_BLOCKS, 256, 0, stream>>>(pos, W1a, b1a, E);
    for (int p = 0; p < NW; p++)
        k_edge<<<EDGE_BLOCKS, 256, 0, stream>>>(srcS, ends, cnt2, pos, E,
                                                W1a + 3 * H, Wpk, b1b,
                                                agg, batch, g, 0, p);
    k_pre2<<<NODE_BLOCKS, 256, 0, stream>>>(pos, agg, W2a, b2a, E);
    for (int p = 0; p < NW; p++)
        k_edge<<<EDGE_BLOCKS, 256, 0, stream>>>(srcS, ends, cnt2, pos, E,
                                                W2a + 32 * H, Wpk + 1024, b2b,
                                                agg, batch, g, 1, p);
    k_out<<<1, 256, 0, stream>>>(g, Wout, bout, out);
}

// Round 17
// 658.160 us; speedup vs baseline: 1.2816x; 1.2816x over previous
//
#include <hip/hip_runtime.h>

#define NN 100000
#define NE 3200000
#define NG 256
#define H 32
#define SB ((NN + 255) / 256)    // 391 scan blocks
#define NB 98                    // dst buckets: (99999>>10)+1
#define BK_SH 10
#define PART_BLOCKS ((NE + 4095) / 4096)   // 782

typedef __attribute__((ext_vector_type(8))) short b16x8;   // 8 bf16 = 4 VGPRs
typedef __attribute__((ext_vector_type(4))) float f32x4;

union ABfrag { unsigned u[4]; b16x8 v; };

// init g=0 (pool accumulator; pooled values >=0 so raw-bit u32 max works),
// hist=0, bktcnt=0. Grid 391x256 covers NN.
__global__ __launch_bounds__(256) void k_init(unsigned* __restrict__ g,
                                              unsigned* __restrict__ hist,
                                              unsigned* __restrict__ bktcnt) {
    int i = blockIdx.x * 256 + threadIdx.x;
    if (i < NG * H) g[i] = 0u;
    if (i < NN) hist[i] = 0u;
    if (i < NB) bktcnt[i] = 0u;
}

// Pack Wb (32x32) of both layers into MFMA B-fragments, bf16 hi/lo split.
// B[k][n] for half h: value W[k*32 + h*16 + n]; lane l holds col n=l&15,
// k = 8*(l>>4)+i (pairs packed low-short-first).
__global__ __launch_bounds__(64) void k_packw(const float* __restrict__ W1b,
                                              const float* __restrict__ W2b,
                                              unsigned* __restrict__ Wpk) {
    int l = threadIdx.x;
    int n = l & 15, gq = l >> 4;
    for (int layer = 0; layer < 2; layer++) {
        const float* W = layer ? W2b : W1b;
        for (int h = 0; h < 2; h++) {
            unsigned hi[8], lo[8];
#pragma unroll
            for (int i = 0; i < 8; i++) {
                float w = W[(8 * gq + i) * H + h * 16 + n];
                unsigned wb = __float_as_uint(w);
                unsigned hb = wb & 0xffff0000u;
                float r = w - __uint_as_float(hb);
                hi[i] = hb;
                lo[i] = __float_as_uint(r) & 0xffff0000u;
            }
            unsigned* dh = Wpk + (((layer * 4 + h * 2 + 0) * 64) + l) * 4;
            unsigned* dl = Wpk + (((layer * 4 + h * 2 + 1) * 64) + l) * 4;
#pragma unroll
            for (int w2 = 0; w2 < 4; w2++) {
                dh[w2] = (hi[2 * w2] >> 16) | (hi[2 * w2 + 1] & 0xffff0000u);
                dl[w2] = (lo[2 * w2] >> 16) | (lo[2 * w2 + 1] & 0xffff0000u);
            }
        }
    }
}

// Per-dst histogram + per-bucket counts (LDS-accumulated, one flush per block).
__global__ __launch_bounds__(256) void k_hist(const int* __restrict__ dst,
                                              unsigned* __restrict__ hist,
                                              unsigned* __restrict__ bktcnt) {
    __shared__ unsigned lb[NB];
    int tid = threadIdx.x;
    if (tid < NB) lb[tid] = 0u;
    __syncthreads();
    int base = blockIdx.x * 4096 + tid;
    for (int c = 0; c < 16; c++) {
        int e = base + c * 256;
        if (e < NE) {
            int d = dst[e];
            atomicAdd(&hist[d], 1u);
            atomicAdd(&lb[d >> BK_SH], 1u);
        }
    }
    __syncthreads();
    if (tid < NB) {
        unsigned v = lb[tid];
        if (v) atomicAdd(&bktcnt[tid], v);
    }
}

// Block-level exclusive scan (Hillis-Steele in LDS), 256 elems/block.
__global__ __launch_bounds__(256) void k_scan1(const unsigned* __restrict__ hist,
                                               unsigned* __restrict__ pre,
                                               unsigned* __restrict__ bsum) {
    __shared__ unsigned sd[256];
    int tid = threadIdx.x;
    int i = blockIdx.x * 256 + tid;
    unsigned v = (i < NN) ? hist[i] : 0u;
    sd[tid] = v;
    __syncthreads();
    for (int off = 1; off < 256; off <<= 1) {
        unsigned t = (tid >= off) ? sd[tid - off] : 0u;
        __syncthreads();
        sd[tid] += t;
        __syncthreads();
    }
    if (i < NN) pre[i] = sd[tid] - v;
    if (tid == 255) bsum[blockIdx.x] = sd[255];
}

__global__ __launch_bounds__(512) void k_scan2(const unsigned* __restrict__ bsum,
                                               unsigned* __restrict__ bpre) {
    __shared__ unsigned sd[512];
    int t = threadIdx.x;
    unsigned v = (t < SB) ? bsum[t] : 0u;
    sd[t] = v;
    __syncthreads();
    for (int off = 1; off < 512; off <<= 1) {
        unsigned x = (t >= off) ? sd[t - off] : 0u;
        __syncthreads();
        sd[t] += x;
        __syncthreads();
    }
    if (t < SB) bpre[t] = sd[t] - v;
}

// cursors[i] = CSR start (scatter cursor for pass B); ends[i] = start+count.
__global__ __launch_bounds__(256) void k_scan3(const unsigned* __restrict__ pre,
                                               const unsigned* __restrict__ bpre,
                                               const unsigned* __restrict__ hist,
                                               unsigned* __restrict__ cursors,
                                               unsigned* __restrict__ ends) {
    int i = blockIdx.x * 256 + threadIdx.x;
    if (i < NN) {
        unsigned o = pre[i] + bpre[blockIdx.x];
        cursors[i] = o;
        ends[i] = o + hist[i];
    }
}

// Tiny exclusive scan of the 98 bucket counts (1 block of 128).
__global__ __launch_bounds__(128) void k_bscan(const unsigned* __restrict__ bktcnt,
                                               unsigned* __restrict__ bktbase,
                                               unsigned* __restrict__ bktcur) {
    __shared__ unsigned sd[128];
    int t = threadIdx.x;
    unsigned v = (t < NB) ? bktcnt[t] : 0u;
    sd[t] = v;
    __syncthreads();
    for (int off = 1; off < 128; off <<= 1) {
        unsigned x = (t >= off) ? sd[t - off] : 0u;
        __syncthreads();
        sd[t] += x;
        __syncthreads();
    }
    if (t < NB) { bktbase[t] = sd[t] - v; bktcur[t] = sd[t] - v; }
    if (t == 127) bktbase[NB] = NE;
}

// Pass A: partition edges into 98 dst-buckets. Per-block LDS hist -> one global
// reservation per bucket -> grouped staging writes (~168B runs; near-full lines).
// staging word = (src << 10) | (dst & 1023); bucket implicit from segment.
__global__ __launch_bounds__(256) void k_part(const int* __restrict__ src,
                                              const int* __restrict__ dst,
                                              unsigned* __restrict__ bktcur,
                                              unsigned* __restrict__ staging) {
    __shared__ unsigned lh[NB], lcur[NB];
    int tid = threadIdx.x;
    if (tid < NB) lh[tid] = 0u;
    __syncthreads();
    int base = blockIdx.x * 4096 + tid;
    for (int c = 0; c < 16; c++) {
        int e = base + c * 256;
        if (e < NE) atomicAdd(&lh[dst[e] >> BK_SH], 1u);
    }
    __syncthreads();
    if (tid < NB) {
        unsigned v = lh[tid];
        lcur[tid] = v ? atomicAdd(&bktcur[tid], v) : 0u;
    }
    __syncthreads();
    for (int c = 0; c < 16; c++) {
        int e = base + c * 256;
        if (e < NE) {
            int d = dst[e], s = src[e];
            unsigned off = atomicAdd(&lcur[d >> BK_SH], 1u);
            staging[off] = ((unsigned)s << BK_SH) | (unsigned)(d & ((1 << BK_SH) - 1));
        }
    }
}

// Pass B: staging (sequential read) -> final dst-sorted srcS. Each bucket's
// writes land in a 128KB srcS window (L2-resident) -> ~no write amplification.
__global__ __launch_bounds__(256) void k_scat2(const unsigned* __restrict__ staging,
                                               const unsigned* __restrict__ bktbase,
                                               unsigned* __restrict__ cursors,
                                               unsigned* __restrict__ srcS) {
    int i = blockIdx.x * 256 + threadIdx.x;   // grid covers exactly NE
    unsigned p = staging[i];
    int lo = 0, hi = NB - 1;                  // find b: bktbase[b] <= i < [b+1]
    while (lo < hi) {
        int mid = (lo + hi + 1) >> 1;
        if ((unsigned)i >= bktbase[mid]) lo = mid; else hi = mid - 1;
    }
    int d = (lo << BK_SH) | (int)(p & ((1u << BK_SH) - 1));
    unsigned slot = atomicAdd(&cursors[d], 1u);
    srcS[slot] = p >> BK_SH;
}

// Layer-1 src-side precompute:
//   E1[n][k] = b1a[k] + sum_i pos[n][i]*(W1a[i][k] + W1a[3+i][k])
__global__ __launch_bounds__(256) void k_pre1(const float* __restrict__ pos,
                                              const float* __restrict__ W1a,
                                              const float* __restrict__ b1a,
                                              float* __restrict__ E) {
    int n = blockIdx.x * 256 + threadIdx.x;
    if (n >= NN) return;
    float p0 = pos[3 * n], p1 = pos[3 * n + 1], p2 = pos[3 * n + 2];
    float ev[H];
#pragma unroll
    for (int k = 0; k < H; k++) {
        float v = b1a[k];
        v = fmaf(p0, W1a[k] + W1a[96 + k], v);
        v = fmaf(p1, W1a[32 + k] + W1a[128 + k], v);
        v = fmaf(p2, W1a[64 + k] + W1a[160 + k], v);
        ev[k] = v;
    }
    float4* E4 = (float4*)(E + (size_t)n * H);
#pragma unroll
    for (int r = 0; r < 8; r++)
        E4[r] = make_float4(ev[4 * r], ev[4 * r + 1], ev[4 * r + 2], ev[4 * r + 3]);
}

// Layer-2 src-side precompute: E2[n][k] = b2a[k] + h1[n]@W2a[0:32][k]
//   + pos[n]@W2a[32:35][k]
__global__ __launch_bounds__(256) void k_pre2(const float* __restrict__ pos,
                                              const float* __restrict__ agg,
                                              const float* __restrict__ W2a,
                                              const float* __restrict__ b2a,
                                              float* __restrict__ E) {
    int n = blockIdx.x * 256 + threadIdx.x;
    if (n >= NN) return;
    float h[H];
    const float4* A4 = (const float4*)(agg + (size_t)n * H);
#pragma unroll
    for (int r = 0; r < 8; r++) {
        float4 u = A4[r];
        h[4 * r + 0] = u.x; h[4 * r + 1] = u.y;
        h[4 * r + 2] = u.z; h[4 * r + 3] = u.w;
    }
    float p0 = pos[3 * n], p1 = pos[3 * n + 1], p2 = pos[3 * n + 2];
    float ev[H];
#pragma unroll
    for (int k = 0; k < H; k++) {
        float v = b2a[k];
        v = fmaf(p0, W2a[32 * H + k], v);
        v = fmaf(p1, W2a[33 * H + k], v);
        v = fmaf(p2, W2a[34 * H + k], v);
        ev[k] = v;
    }
#pragma unroll
    for (int j = 0; j < H; j++) {
        float hj = h[j];
#pragma unroll
        for (int k = 0; k < H; k++) ev[k] = fmaf(hj, W2a[j * H + k], ev[k]);
    }
    float4* E4 = (float4*)(E + (size_t)n * H);
#pragma unroll
    for (int r = 0; r < 8; r++)
        E4[r] = make_float4(ev[4 * r], ev[4 * r + 1], ev[4 * r + 2], ev[4 * r + 3]);
}

// MFMA edge kernel: ONE WAVE PER NODE, 16 EDGES PER TILE (round-14 version —
// the verified optimum; the gather is at the random-line-rate machine limit).
__global__ __launch_bounds__(256) void k_edge(const unsigned* __restrict__ srcS,
                                              const unsigned* __restrict__ ends,
                                              const float* __restrict__ pos,
                                              const float* __restrict__ E,
                                              const float* __restrict__ Wf,
                                              const unsigned* __restrict__ WpkL,
                                              const float* __restrict__ bb,
                                              float* __restrict__ aggOut,
                                              const int* __restrict__ batch,
                                              unsigned* __restrict__ g,
                                              int layer2) {
    int lane = threadIdx.x & 63;
    int node = __builtin_amdgcn_readfirstlane(blockIdx.x * 4 + (threadIdx.x >> 6));
    unsigned start = (node == 0) ? 0u : ends[node - 1];
    int deg = (int)(ends[node] - start);
    int row = lane & 15;       // A row (edge within tile)
    int j0 = (lane >> 4) << 3; // k-block start (channel j for t-generation)
    ABfrag b0h, b0l, b1h, b1l;
    {
        const uint4* W4 = (const uint4*)WpkL;
        *(uint4*)b0h.u = W4[0 * 64 + lane];
        *(uint4*)b0l.u = W4[1 * 64 + lane];
        *(uint4*)b1h.u = W4[2 * 64 + lane];
        *(uint4*)b1l.u = W4[3 * 64 + lane];
    }
    float pd0 = pos[3 * node], pd1 = pos[3 * node + 1], pd2 = pos[3 * node + 2];
    float fd[8];
#pragma unroll
    for (int q = 0; q < 8; q++)
        fd[q] = fmaf(pd0, Wf[j0 + q],
                fmaf(pd1, Wf[32 + j0 + q], pd2 * Wf[64 + j0 + q]));
    f32x4 vmax0 = {-3.0e38f, -3.0e38f, -3.0e38f, -3.0e38f};
    f32x4 vmax1 = vmax0;
    const f32x4 z = {0.f, 0.f, 0.f, 0.f};
    for (int i0 = 0; i0 < deg; i0 += 16) {
        int e = i0 + row;
        if (e >= deg) e = deg - 1;            // duplicate-pad (max-safe)
        int s = (int)srcS[start + e];
        const float* er = E + ((size_t)s << 5) + j0;
        float4 t0 = *(const float4*)er;
        float4 t1 = *(const float4*)(er + 4);
        float t[8] = {t0.x, t0.y, t0.z, t0.w, t1.x, t1.y, t1.z, t1.w};
        ABfrag ah, al;
#pragma unroll
        for (int w = 0; w < 4; w++) {
            float x0 = fmaxf(t[2 * w]     - fd[2 * w],     0.f);
            float x1 = fmaxf(t[2 * w + 1] - fd[2 * w + 1], 0.f);
            unsigned u0 = __float_as_uint(x0), u1 = __float_as_uint(x1);
            ah.u[w] = __builtin_amdgcn_perm(u1, u0, 0x07060302u);
            float r0 = x0 - __uint_as_float(u0 & 0xffff0000u);
            float r1 = x1 - __uint_as_float(u1 & 0xffff0000u);
            al.u[w] = __builtin_amdgcn_perm(__float_as_uint(r1),
                                            __float_as_uint(r0), 0x07060302u);
        }
        f32x4 acc0 = __builtin_amdgcn_mfma_f32_16x16x32_bf16(ah.v, b0h.v, z, 0, 0, 0);
        acc0 = __builtin_amdgcn_mfma_f32_16x16x32_bf16(al.v, b0h.v, acc0, 0, 0, 0);
        acc0 = __builtin_amdgcn_mfma_f32_16x16x32_bf16(ah.v, b0l.v, acc0, 0, 0, 0);
        f32x4 acc1 = __builtin_amdgcn_mfma_f32_16x16x32_bf16(ah.v, b1h.v, z, 0, 0, 0);
        acc1 = __builtin_amdgcn_mfma_f32_16x16x32_bf16(al.v, b1h.v, acc1, 0, 0, 0);
        acc1 = __builtin_amdgcn_mfma_f32_16x16x32_bf16(ah.v, b1l.v, acc1, 0, 0, 0);
#pragma unroll
        for (int r = 0; r < 4; r++) {
            vmax0[r] = fmaxf(vmax0[r], acc0[r]);
            vmax1[r] = fmaxf(vmax1[r], acc1[r]);
        }
    }
    float m0 = fmaxf(fmaxf(vmax0[0], vmax0[1]), fmaxf(vmax0[2], vmax0[3]));
    float m1 = fmaxf(fmaxf(vmax1[0], vmax1[1]), fmaxf(vmax1[2], vmax1[3]));
    m0 = fmaxf(m0, __shfl_xor(m0, 16));
    m0 = fmaxf(m0, __shfl_xor(m0, 32));
    m1 = fmaxf(m1, __shfl_xor(m1, 16));
    m1 = fmaxf(m1, __shfl_xor(m1, 32));
    if (lane < H) {
        float red = (lane < 16) ? m0 : m1;            // ch = lane (0..31)
        float val = (deg > 0) ? fmaxf(red + bb[lane], 0.f) : 0.f;
        if (!layer2) {
            aggOut[(size_t)node * H + lane] = val;    // h1 (relu folded)
        } else {
            int b = batch[node];
            unsigned bits = __float_as_uint(val);     // nonneg: bit order = value
            unsigned* gb = g + ((size_t)b << 5) + lane;
            if (bits > *gb) atomicMax(gb, bits);
        }
    }
}

__global__ __launch_bounds__(256) void k_out(const unsigned* __restrict__ g,
                                             const float* __restrict__ Wout,
                                             const float* __restrict__ bout,
                                             float* __restrict__ out) {
    int bidx = threadIdx.x;  // one block of 256
    float acc = bout[0];
#pragma unroll
    for (int k = 0; k < H; k++)
        acc = fmaf(__uint_as_float(g[bidx * H + k]), Wout[k], acc);
    out[bidx] = acc;
}

extern "C" void kernel_launch(void* const* d_in, const int* in_sizes, int n_in,
                              void* d_out, int out_size, void* d_ws, size_t ws_size,
                              hipStream_t stream) {
    const float* pos  = (const float*)d_in[0];
    const int* src    = (const int*)d_in[1];
    const int* dst    = src + NE;
    const int* batch  = (const int*)d_in[2];
    const float* W1a  = (const float*)d_in[3];
    const float* b1a  = (const float*)d_in[4];
    const float* W1b  = (const float*)d_in[5];
    const float* b1b  = (const float*)d_in[6];
    const float* W2a  = (const float*)d_in[7];
    const float* b2a  = (const float*)d_in[8];
    const float* W2b  = (const float*)d_in[9];
    const float* b2b  = (const float*)d_in[10];
    const float* Wout = (const float*)d_in[11];
    const float* bout = (const float*)d_in[12];
    float* out = (float*)d_out;

    const size_t SZ = (size_t)NN * H;  // 3.2M words
    float*    agg  = (float*)d_ws;                   // 12.8 MB (h1)
    float*    E    = (float*)d_ws + SZ;              // 12.8 MB (E1/E2)
    unsigned* srcS = (unsigned*)d_ws + 2 * SZ;       // 12.8 MB (dst-sorted src)
    unsigned* g    = (unsigned*)d_ws + 3 * SZ;       // 32 KB (pool)
    unsigned* ends = g + NG * H;                     // 400 KB (CSR ends)
    unsigned* bsum = ends + NN;                      // scan partials
    unsigned* bpre = bsum + SB + 1;
    unsigned* Wpk  = bpre + SB + 1;                  // 16 KB (B-fragments)
    unsigned* bktcnt  = Wpk + 4096;                  // NB
    unsigned* bktbase = bktcnt + NB;                 // NB+1
    unsigned* bktcur  = bktbase + NB + 1;            // NB
    // Aliased temporaries:
    //   agg's space (dead until k_edge L1): hist, pre, cursors
    //   E's space   (dead until k_pre1):    staging (NE u32 == SZ exactly)
    unsigned* hist    = (unsigned*)agg;
    unsigned* pre     = hist + NN;
    unsigned* cursors = pre + NN;
    unsigned* staging = (unsigned*)E;

    const int NODE_BLOCKS = SB;          // 391
    const int SCAT_BLOCKS = NE / 256;    // 12500 (k_scat2, exact)
    const int WAVE_BLOCKS = NN / 4;      // 25000 (4 node-waves/block, exact)

    k_init<<<NODE_BLOCKS, 256, 0, stream>>>(g, hist, bktcnt);
    k_packw<<<1, 64, 0, stream>>>(W1b, W2b, Wpk);
    k_hist<<<PART_BLOCKS, 256, 0, stream>>>(dst, hist, bktcnt);
    k_scan1<<<NODE_BLOCKS, 256, 0, stream>>>(hist, pre, bsum);
    k_scan2<<<1, 512, 0, stream>>>(bsum, bpre);
    k_scan3<<<NODE_BLOCKS, 256, 0, stream>>>(pre, bpre, hist, cursors, ends);
    k_bscan<<<1, 128, 0, stream>>>(bktcnt, bktbase, bktcur);
    k_part<<<PART_BLOCKS, 256, 0, stream>>>(src, dst, bktcur, staging);
    k_scat2<<<SCAT_BLOCKS, 256, 0, stream>>>(staging, bktbase, cursors, srcS);
    k_pre1<<<NODE_BLOCKS, 256, 0, stream>>>(pos, W1a, b1a, E);
    k_edge<<<WAVE_BLOCKS, 256, 0, stream>>>(srcS, ends, pos, E,
                                            W1a + 3 * H, Wpk, b1b,
                                            agg, batch, g, 0);
    k_pre2<<<NODE_BLOCKS, 256, 0, stream>>>(pos, agg, W2a, b2a, E);
    k_edge<<<WAVE_BLOCKS, 256, 0, stream>>>(srcS, ends, pos, E,
                                            W2a + 32 * H, Wpk + 1024, b2b,
                                            agg, batch, g, 1);
    k_out<<<1, 256, 0, stream>>>(g, Wout, bout, out);
}